// Round 1
// baseline (1170.394 us; speedup 1.0000x reference)
//
#include <hip/hip_runtime.h>
#include <stdint.h>

// Problem constants
#define T_  512
#define B_  256
#define F_  512
#define H_  128
#define MH_ 64
#define A_  8
#define OUT0 1179648   // T*B*(A+1)
#define OUT1 32768     // B*H

typedef float f32x4 __attribute__((ext_vector_type(4)));
typedef __bf16 bfrag8 __attribute__((ext_vector_type(8)));
typedef unsigned short u16;
typedef unsigned int u32;

// Workspace layout (bytes)
#define WS_GATES 0u
#define WS_HSEQ  134217728u
#define WS_WIH   167772160u
#define WS_WHH   168296448u
#define WS_WP1   168427520u
#define WS_WV1   168443904u

__device__ inline u16 f2bf(float f) {
  union { float f; u32 u; } v; v.f = f;
  u32 u = v.u;
  u32 r = (u + 0x7FFFu + ((u >> 16) & 1u)) >> 16;
  return (u16)r;
}
__device__ inline float bf2f(u16 b) {
  union { u32 u; float f; } v; v.u = ((u32)b) << 16;
  return v.f;
}

__device__ inline float fexp2(float x) {
#if __has_builtin(__builtin_amdgcn_exp2f)
  return __builtin_amdgcn_exp2f(x);
#else
  return exp2f(x);
#endif
}
__device__ inline float frcp(float x) {
#if __has_builtin(__builtin_amdgcn_rcpf)
  return __builtin_amdgcn_rcpf(x);
#else
  return 1.0f / x;
#endif
}
__device__ inline float sig_(float x) {
  return frcp(1.0f + fexp2(-1.44269504f * x));
}
__device__ inline float tanh_(float x) {
  x = fminf(30.0f, fmaxf(-30.0f, x));
  float t = fexp2(2.88539008f * x);
  return (t - 1.0f) * frcp(t + 1.0f);
}

__device__ inline f32x4 mfma16(bfrag8 a, bfrag8 b, f32x4 c) {
  return __builtin_amdgcn_mfma_f32_16x16x32_bf16(a, b, c, 0, 0, 0);
}

__device__ inline void gld16(const void* g, void* l) {
  __builtin_amdgcn_global_load_lds((const __attribute__((address_space(1))) void*)g,
                                   (__attribute__((address_space(3))) void*)l, 16, 0, 0);
}

// ---------------- Kernel 0: weight conversion / swizzle ----------------
// W_ih -> fragment-chunk layout: chunk(ntile,kblk) is 64 lanes x 8 bf16,
// element (L,i) = W_ih[ntile*16 + (L&15)][kblk*32 + (L>>4)*8 + i]
__global__ __launch_bounds__(256) void k0_prep(const float* __restrict__ W_ih,
                                               const float* __restrict__ W_hh,
                                               const float* __restrict__ W_p1,
                                               const float* __restrict__ W_v1,
                                               u16* __restrict__ wih_swz,
                                               u16* __restrict__ whh_bf,
                                               u16* __restrict__ wp1s,
                                               u16* __restrict__ wv1s) {
  int idx = blockIdx.x * 256 + threadIdx.x;
  if (idx < 262144) {
    int i = idx & 7, L = (idx >> 3) & 63, kb = (idx >> 9) & 15, nt = idx >> 13;
    wih_swz[idx] = f2bf(W_ih[(nt * 16 + (L & 15)) * 512 + kb * 32 + ((L >> 4) << 3) + i]);
  } else if (idx < 262144 + 65536) {
    int j = idx - 262144;
    whh_bf[j] = f2bf(W_hh[j]);
  } else if (idx < 262144 + 65536 + 8192) {
    int j = idx - (262144 + 65536);
    int i = j & 7, L = (j >> 3) & 63, kb = (j >> 9) & 3, nt = j >> 11;
    wp1s[j] = f2bf(W_p1[(kb * 32 + ((L >> 4) << 3) + i) * 64 + nt * 16 + (L & 15)]);
  } else if (idx < 262144 + 65536 + 16384) {
    int j = idx - (262144 + 65536 + 8192);
    int i = j & 7, L = (j >> 3) & 63, kb = (j >> 9) & 3, nt = j >> 11;
    wv1s[j] = f2bf(W_v1[(kb * 32 + ((L >> 4) << 3) + i) * 64 + nt * 16 + (L & 15)]);
  }
}

// ---------------- Kernel 1: gates_pre = x @ W_ih^T + b_ih + b_hh (bf16 out) ----------------
// 128x128 tile, BK=64, 4 waves each computing 4x4 16x16 tiles.
__global__ __launch_bounds__(256) void k1_gates(const float* __restrict__ x,
                                                const u16* __restrict__ wih_swz,
                                                const float* __restrict__ b_ih,
                                                const float* __restrict__ b_hh,
                                                u16* __restrict__ gates) {
  __shared__ __align__(16) u16 Abuf[16 * 64 * 8];  // [chunk=mt*2+kb][lane][8]
  __shared__ __align__(16) u16 Bbuf[16 * 64 * 8];  // [chunk=nt*2+kb][lane][8]
  const int tid = threadIdx.x;
  const int lane = tid & 63;
  const int w = tid >> 6;
  const int lrow = lane >> 4, lcol = lane & 15;
  const int m0 = (blockIdx.x >> 2) * 128;
  const int n0 = (blockIdx.x & 3) * 128;
  const int mt0 = (w & 1) * 4, nt0 = (w >> 1) * 4;
  f32x4 acc[4][4] = {};

  for (int k0 = 0; k0 < 512; k0 += 64) {
    // B staging via async global->LDS (weights pre-swizzled, lane-linear)
#pragma unroll
    for (int cc = 0; cc < 4; ++cc) {
      int c = w * 4 + cc;
      int ntg = (n0 >> 4) + (c >> 1);
      int kbg = (k0 >> 5) + (c & 1);
      gld16(wih_swz + (ntg * 16 + kbg) * 512 + lane * 8, &Bbuf[c * 512]);
    }
    // A staging: fp32 load -> bf16 convert -> fragment-chunk LDS layout
#pragma unroll
    for (int j = 0; j < 8; ++j) {
      int s = tid + 256 * j;            // 0..2047, one float4 each
      int c = s >> 7, L = (s >> 1) & 63, hh = s & 1;
      int mt = c >> 1, kb = c & 1;
      const float4 v = *(const float4*)&x[(m0 + mt * 16 + (L & 15)) * 512 +
                                          k0 + kb * 32 + ((L >> 4) << 3) + hh * 4];
      ushort4 pk;
      pk.x = f2bf(v.x); pk.y = f2bf(v.y); pk.z = f2bf(v.z); pk.w = f2bf(v.w);
      *(ushort4*)&Abuf[(c * 64 + L) * 8 + hh * 4] = pk;
    }
    __syncthreads();
#pragma unroll
    for (int kk = 0; kk < 2; ++kk) {
      bfrag8 af[4], bfr[4];
#pragma unroll
      for (int im = 0; im < 4; ++im)
        af[im] = *(const bfrag8*)&Abuf[(((mt0 + im) * 2 + kk) * 64 + lane) * 8];
#pragma unroll
      for (int in = 0; in < 4; ++in)
        bfr[in] = *(const bfrag8*)&Bbuf[(((nt0 + in) * 2 + kk) * 64 + lane) * 8];
#pragma unroll
      for (int im = 0; im < 4; ++im)
#pragma unroll
        for (int in = 0; in < 4; ++in)
          acc[im][in] = mfma16(af[im], bfr[in], acc[im][in]);
    }
    __syncthreads();
  }
  // epilogue: add bias, store bf16
#pragma unroll
  for (int in = 0; in < 4; ++in) {
    int n = n0 + (nt0 + in) * 16 + lcol;
    float bias = b_ih[n] + b_hh[n];
#pragma unroll
    for (int im = 0; im < 4; ++im) {
      int mbase = m0 + (mt0 + im) * 16 + lrow * 4;
#pragma unroll
      for (int r = 0; r < 4; ++r)
        gates[(mbase + r) * 512 + n] = f2bf(acc[im][in][r] + bias);
    }
  }
}

// ---------------- Kernel 2: sequential masked LSTM ----------------
// 16 blocks x 512 threads; block b handles batches [16b,16b+16).
// h lives in LDS (double-buffered bf16), c in registers for all 512 steps.
// Batch independence => no grid sync, only one __syncthreads per step.
__global__ __launch_bounds__(512) void k2_lstm(const float* __restrict__ done,
                                               const float* __restrict__ h0,
                                               const float* __restrict__ c0,
                                               const u16* __restrict__ whh_bf,
                                               const u16* __restrict__ gates,
                                               u16* __restrict__ hseq,
                                               float* __restrict__ dout) {
  __shared__ __align__(16) u16 h_lds[2][16][136];  // +8 pad: conflict-free A-frag reads
  const int tid = threadIdx.x;
  const int lane = tid & 63;
  const int w = tid >> 6;            // 0..7, owns h-cols [16w,16w+16)
  const int lrow = lane >> 4, lcol = lane & 15;
  const int bbase = blockIdx.x * 16;
  const int jb = w * 16;

  // Preload W_hh fragments for all 4 gates x 4 K-steps (64 VGPRs, reused 512x)
  bfrag8 wf[4][4];
#pragma unroll
  for (int g = 0; g < 4; ++g)
#pragma unroll
    for (int kk = 0; kk < 4; ++kk)
      wf[g][kk] = *(const bfrag8*)&whh_bf[(g * 128 + jb + lcol) * 128 + kk * 32 + lrow * 8];

  // init h_lds[0] = h0 * (1 - done[0])
  {
    int e = tid * 4;                  // 512 threads x 4 = 2048 = 16*128
    int row = e >> 7, col = e & 127;
    float m = 1.0f - done[bbase + row];
    const float4 hv = *(const float4*)&h0[(bbase + row) * 128 + col];
    h_lds[0][row][col]     = f2bf(hv.x * m);
    h_lds[0][row][col + 1] = f2bf(hv.y * m);
    h_lds[0][row][col + 2] = f2bf(hv.z * m);
    h_lds[0][row][col + 3] = f2bf(hv.w * m);
  }
  // init c (C-layout rows) with done[0] mask
  float c[4], hfin[4];
  {
    const float4 d0 = *(const float4*)&done[bbase + lrow * 4];
    c[0] = c0[(bbase + lrow * 4 + 0) * 128 + jb + lcol] * (1.0f - d0.x);
    c[1] = c0[(bbase + lrow * 4 + 1) * 128 + jb + lcol] * (1.0f - d0.y);
    c[2] = c0[(bbase + lrow * 4 + 2) * 128 + jb + lcol] * (1.0f - d0.z);
    c[3] = c0[(bbase + lrow * 4 + 3) * 128 + jb + lcol] * (1.0f - d0.w);
    hfin[0] = hfin[1] = hfin[2] = hfin[3] = 0.0f;
  }
  // prefetch gates_pre for t=0 into registers
  u32 gp[16], gpn[16];
#pragma unroll
  for (int g = 0; g < 4; ++g)
#pragma unroll
    for (int r = 0; r < 4; ++r)
      gp[g * 4 + r] = gates[(bbase + lrow * 4 + r) * 512 + g * 128 + jb + lcol];

  for (int t = 0; t < T_; ++t) {
    const int cur = t & 1, nxt = cur ^ 1;
    __syncthreads();  // h_lds[cur] writes visible; prefetched loads drained

    // register prefetch of gates_pre for t+1 (full step of lead time)
    const int tn = (t < T_ - 1) ? (t + 1) : (T_ - 1);
#pragma unroll
    for (int g = 0; g < 4; ++g)
#pragma unroll
      for (int r = 0; r < 4; ++r)
        gpn[g * 4 + r] = gates[(tn * B_ + bbase + lrow * 4 + r) * 512 + g * 128 + jb + lcol];
    const float4 dn = *(const float4*)&done[tn * B_ + bbase + lrow * 4];
    const float live = (t < T_ - 1) ? 1.0f : 0.0f;
    float mk[4];
    mk[0] = 1.0f - live * dn.x;
    mk[1] = 1.0f - live * dn.y;
    mk[2] = 1.0f - live * dn.z;
    mk[3] = 1.0f - live * dn.w;

    // h fragments from LDS
    bfrag8 af[4];
#pragma unroll
    for (int kk = 0; kk < 4; ++kk)
      af[kk] = *(const bfrag8*)&h_lds[cur][lcol][kk * 32 + lrow * 8];

    f32x4 acc[4] = {};
#pragma unroll
    for (int kk = 0; kk < 4; ++kk)
#pragma unroll
      for (int g = 0; g < 4; ++g)
        acc[g] = mfma16(af[kk], wf[g][kk], acc[g]);

#pragma unroll
    for (int r = 0; r < 4; ++r) {
      float pi = acc[0][r] + bf2f((u16)gp[0 * 4 + r]);
      float pf = acc[1][r] + bf2f((u16)gp[1 * 4 + r]);
      float pg = acc[2][r] + bf2f((u16)gp[2 * 4 + r]);
      float po = acc[3][r] + bf2f((u16)gp[3 * 4 + r]);
      float iv = sig_(pi), fv = sig_(pf), gv = tanh_(pg), ov = sig_(po);
      float cc = fv * c[r] + iv * gv;
      float hh = ov * tanh_(cc);
      c[r] = cc * mk[r];
      hfin[r] = hh;
      hseq[((t * B_ + bbase + lrow * 4 + r) << 7) + jb + lcol] = f2bf(hh);
      h_lds[nxt][lrow * 4 + r][jb + lcol] = f2bf(hh * mk[r]);
    }
#pragma unroll
    for (int q = 0; q < 16; ++q) gp[q] = gpn[q];
  }
  // hT, cT (fp32)
#pragma unroll
  for (int r = 0; r < 4; ++r) {
    int bg = bbase + lrow * 4 + r;
    dout[OUT0 + bg * 128 + jb + lcol] = hfin[r];
    dout[OUT0 + OUT1 + bg * 128 + jb + lcol] = c[r];
  }
}

// ---------------- Kernel 3: MLP heads ----------------
// block = 64 rows; MFMA for hseq@W_p1 / @W_v1, tanh, then VALU N=8/N=1 GEMM.
__global__ __launch_bounds__(256) void k3_heads(const u16* __restrict__ hseq,
                                                const u16* __restrict__ wp1s,
                                                const u16* __restrict__ wv1s,
                                                const float* __restrict__ b_p1,
                                                const float* __restrict__ W_p2,
                                                const float* __restrict__ b_p2,
                                                const float* __restrict__ b_v1,
                                                const float* __restrict__ W_v2,
                                                const float* __restrict__ b_v2,
                                                float* __restrict__ out) {
  __shared__ float midp[4][16][68];
  __shared__ float midv[4][16][68];
  __shared__ float wsm[585];  // W_p2(512) ++ W_v2(64) ++ b_p2(8) ++ b_v2(1)
  const int tid = threadIdx.x;
  const int lane = tid & 63, w = tid >> 6;
  const int lrow = lane >> 4, lcol = lane & 15;
  const int r0 = blockIdx.x * 64;

  for (int e = tid; e < 585; e += 256) {
    float v;
    if (e < 512) v = W_p2[e];
    else if (e < 576) v = W_v2[e - 512];
    else if (e < 584) v = b_p2[e - 576];
    else v = b_v2[0];
    wsm[e] = v;
  }

  const int rowA = r0 + w * 16 + lcol;  // A-frag m = lane&15
  bfrag8 af[4];
#pragma unroll
  for (int kk = 0; kk < 4; ++kk)
    af[kk] = *(const bfrag8*)&hseq[rowA * 128 + kk * 32 + lrow * 8];

#pragma unroll
  for (int nt = 0; nt < 4; ++nt) {
    f32x4 ap = {}, av = {};
#pragma unroll
    for (int kk = 0; kk < 4; ++kk) {
      ap = mfma16(af[kk], *(const bfrag8*)&wp1s[((nt * 4 + kk) * 64 + lane) * 8], ap);
      av = mfma16(af[kk], *(const bfrag8*)&wv1s[((nt * 4 + kk) * 64 + lane) * 8], av);
    }
    float bp = b_p1[nt * 16 + lcol], bv = b_v1[nt * 16 + lcol];
#pragma unroll
    for (int r = 0; r < 4; ++r) {
      midp[w][lrow * 4 + r][nt * 16 + lcol] = tanh_(ap[r] + bp);
      midv[w][lrow * 4 + r][nt * 16 + lcol] = tanh_(av[r] + bv);
    }
  }
  __syncthreads();

  for (int o = tid; o < 576; o += 256) {
    int row = o / 9;
    int a = o - row * 9;
    float s;
    if (a < 8) {
      s = wsm[576 + a];
      const float* mrow = &midp[row >> 4][row & 15][0];
#pragma unroll
      for (int n = 0; n < 64; ++n) s += mrow[n] * wsm[n * 8 + a];
    } else {
      s = wsm[584];
      const float* mrow = &midv[row >> 4][row & 15][0];
#pragma unroll
      for (int n = 0; n < 64; ++n) s += mrow[n] * wsm[512 + n];
    }
    out[(r0 + row) * 9 + a] = s;
  }
}

extern "C" void kernel_launch(void* const* d_in, const int* in_sizes, int n_in,
                              void* d_out, int out_size, void* d_ws, size_t ws_size,
                              hipStream_t stream) {
  const float* x    = (const float*)d_in[0];
  const float* done = (const float*)d_in[1];
  const float* h0   = (const float*)d_in[2];
  const float* c0   = (const float*)d_in[3];
  const float* W_ih = (const float*)d_in[4];
  const float* W_hh = (const float*)d_in[5];
  const float* b_ih = (const float*)d_in[6];
  const float* b_hh = (const float*)d_in[7];
  const float* W_p1 = (const float*)d_in[8];
  const float* b_p1 = (const float*)d_in[9];
  const float* W_p2 = (const float*)d_in[10];
  const float* b_p2 = (const float*)d_in[11];
  const float* W_v1 = (const float*)d_in[12];
  const float* b_v1 = (const float*)d_in[13];
  const float* W_v2 = (const float*)d_in[14];
  const float* b_v2 = (const float*)d_in[15];

  char* ws = (char*)d_ws;
  u16* gates   = (u16*)(ws + WS_GATES);
  u16* hseq    = (u16*)(ws + WS_HSEQ);
  u16* wih_swz = (u16*)(ws + WS_WIH);
  u16* whh_bf  = (u16*)(ws + WS_WHH);
  u16* wp1s    = (u16*)(ws + WS_WP1);
  u16* wv1s    = (u16*)(ws + WS_WV1);
  float* out = (float*)d_out;

  k0_prep<<<dim3(1344), dim3(256), 0, stream>>>(W_ih, W_hh, W_p1, W_v1,
                                                wih_swz, whh_bf, wp1s, wv1s);
  k1_gates<<<dim3(4096), dim3(256), 0, stream>>>(x, wih_swz, b_ih, b_hh, gates);
  k2_lstm<<<dim3(16), dim3(512), 0, stream>>>(done, h0, c0, whh_bf, gates, hseq, out);
  k3_heads<<<dim3(2048), dim3(256), 0, stream>>>(hseq, wp1s, wv1s, b_p1, W_p2, b_p2,
                                                 b_v1, W_v2, b_v2, out);
}

// Round 2
// 837.674 us; speedup vs baseline: 1.3972x; 1.3972x over previous
//
#include <hip/hip_runtime.h>
#include <stdint.h>

// Problem constants
#define T_  512
#define B_  256
#define F_  512
#define H_  128
#define MH_ 64
#define A_  8
#define OUT0 1179648   // T*B*(A+1)
#define OUT1 32768     // B*H

typedef float f32x4 __attribute__((ext_vector_type(4)));
typedef __bf16 bfrag8 __attribute__((ext_vector_type(8)));
typedef unsigned short u16;
typedef unsigned int u32;

// Workspace layout (bytes)
#define WS_GATES 0u
#define WS_HSEQ  134217728u
#define WS_WIH   167772160u
#define WS_WHH   168296448u
#define WS_WP1   168427520u
#define WS_WV1   168443904u

__device__ inline u16 f2bf(float f) {
  union { float f; u32 u; } v; v.f = f;
  u32 u = v.u;
  u32 r = (u + 0x7FFFu + ((u >> 16) & 1u)) >> 16;
  return (u16)r;
}
__device__ inline float bf2f(u16 b) {
  union { u32 u; float f; } v; v.u = ((u32)b) << 16;
  return v.f;
}

__device__ inline float fexp2(float x) {
#if __has_builtin(__builtin_amdgcn_exp2f)
  return __builtin_amdgcn_exp2f(x);
#else
  return exp2f(x);
#endif
}
__device__ inline float frcp(float x) {
#if __has_builtin(__builtin_amdgcn_rcpf)
  return __builtin_amdgcn_rcpf(x);
#else
  return 1.0f / x;
#endif
}
__device__ inline float sig_(float x) {
  return frcp(1.0f + fexp2(-1.44269504f * x));
}
__device__ inline float tanh_(float x) {
  x = fminf(30.0f, fmaxf(-30.0f, x));
  float t = fexp2(2.88539008f * x);
  return (t - 1.0f) * frcp(t + 1.0f);
}
// select a[q] from f32x4 with 3 cndmasks (q in 0..3, per-lane)
__device__ inline float sel4(f32x4 a, int q) {
  float s01 = (q & 1) ? a[1] : a[0];
  float s23 = (q & 1) ? a[3] : a[2];
  return (q & 2) ? s23 : s01;
}

__device__ inline f32x4 mfma16(bfrag8 a, bfrag8 b, f32x4 c) {
  return __builtin_amdgcn_mfma_f32_16x16x32_bf16(a, b, c, 0, 0, 0);
}

__device__ inline void gld16(const void* g, void* l) {
  __builtin_amdgcn_global_load_lds((const __attribute__((address_space(1))) void*)g,
                                   (__attribute__((address_space(3))) void*)l, 16, 0, 0);
}

// ---------------- Kernel 0: weight conversion / swizzle ----------------
__global__ __launch_bounds__(256) void k0_prep(const float* __restrict__ W_ih,
                                               const float* __restrict__ W_hh,
                                               const float* __restrict__ W_p1,
                                               const float* __restrict__ W_v1,
                                               u16* __restrict__ wih_swz,
                                               u16* __restrict__ whh_bf,
                                               u16* __restrict__ wp1s,
                                               u16* __restrict__ wv1s) {
  int idx = blockIdx.x * 256 + threadIdx.x;
  if (idx < 262144) {
    int i = idx & 7, L = (idx >> 3) & 63, kb = (idx >> 9) & 15, nt = idx >> 13;
    wih_swz[idx] = f2bf(W_ih[(nt * 16 + (L & 15)) * 512 + kb * 32 + ((L >> 4) << 3) + i]);
  } else if (idx < 262144 + 65536) {
    int j = idx - 262144;
    whh_bf[j] = f2bf(W_hh[j]);
  } else if (idx < 262144 + 65536 + 8192) {
    int j = idx - (262144 + 65536);
    int i = j & 7, L = (j >> 3) & 63, kb = (j >> 9) & 3, nt = j >> 11;
    wp1s[j] = f2bf(W_p1[(kb * 32 + ((L >> 4) << 3) + i) * 64 + nt * 16 + (L & 15)]);
  } else if (idx < 262144 + 65536 + 16384) {
    int j = idx - (262144 + 65536 + 8192);
    int i = j & 7, L = (j >> 3) & 63, kb = (j >> 9) & 3, nt = j >> 11;
    wv1s[j] = f2bf(W_v1[(kb * 32 + ((L >> 4) << 3) + i) * 64 + nt * 16 + (L & 15)]);
  }
}

// ---------------- Kernel 1: gates_pre = x @ W_ih^T + b_ih + b_hh (bf16 out) ----------------
// 128M x 512N per block (1024 blocks): x is read exactly once from HBM.
// 8 waves as 2(M) x 4(N): each wave 4 m-tiles x 8 n-tiles, BK=64.
__global__ __launch_bounds__(512) void k1_gates(const float* __restrict__ x,
                                                const u16* __restrict__ wih_swz,
                                                const float* __restrict__ b_ih,
                                                const float* __restrict__ b_hh,
                                                u16* __restrict__ gates) {
  __shared__ __align__(16) u16 Abuf[16 * 64 * 8];  // 16 KB: chunks (mt 0..7, kb 0..1)
  __shared__ __align__(16) u16 Bbuf[64 * 64 * 8];  // 64 KB: chunks (nt 0..31, kb 0..1)
  const int tid = threadIdx.x;
  const int lane = tid & 63;
  const int w = tid >> 6;
  const int lrow = lane >> 4, lcol = lane & 15;
  const int m0 = blockIdx.x * 128;
  const int mt0 = (w & 1) * 4, nt0 = (w >> 1) * 8;
  f32x4 acc[4][8] = {};

  for (int k0 = 0; k0 < 512; k0 += 64) {
    // B staging: 64 chunks via async global->LDS, 8 per wave
#pragma unroll
    for (int cc = 0; cc < 8; ++cc) {
      int c = w * 8 + cc;
      int ntg = c >> 1;
      int kbg = (k0 >> 5) + (c & 1);
      gld16(wih_swz + (ntg * 16 + kbg) * 512 + lane * 8, &Bbuf[c * 512]);
    }
    // A staging: fp32 -> bf16, fragment-chunk layout; 2048 float4 / 512 thr = 4 each
#pragma unroll
    for (int j = 0; j < 4; ++j) {
      int s = tid + 512 * j;
      int c = s >> 7, L = (s >> 1) & 63, hh = s & 1;
      int mt = c >> 1, kb = c & 1;
      const float4 v = *(const float4*)&x[(m0 + mt * 16 + (L & 15)) * 512 +
                                          k0 + kb * 32 + ((L >> 4) << 3) + hh * 4];
      ushort4 pk;
      pk.x = f2bf(v.x); pk.y = f2bf(v.y); pk.z = f2bf(v.z); pk.w = f2bf(v.w);
      *(ushort4*)&Abuf[(c * 64 + L) * 8 + hh * 4] = pk;
    }
    __syncthreads();
#pragma unroll
    for (int kk = 0; kk < 2; ++kk) {
      bfrag8 af[4], bfr[8];
#pragma unroll
      for (int im = 0; im < 4; ++im)
        af[im] = *(const bfrag8*)&Abuf[(((mt0 + im) * 2 + kk) * 64 + lane) * 8];
#pragma unroll
      for (int in = 0; in < 8; ++in)
        bfr[in] = *(const bfrag8*)&Bbuf[(((nt0 + in) * 2 + kk) * 64 + lane) * 8];
#pragma unroll
      for (int im = 0; im < 4; ++im)
#pragma unroll
        for (int in = 0; in < 8; ++in)
          acc[im][in] = mfma16(af[im], bfr[in], acc[im][in]);
    }
    __syncthreads();
  }
  // epilogue: add bias, store bf16
#pragma unroll
  for (int in = 0; in < 8; ++in) {
    int n = (nt0 + in) * 16 + lcol;
    float bias = b_ih[n] + b_hh[n];
#pragma unroll
    for (int im = 0; im < 4; ++im) {
      int mbase = m0 + (mt0 + im) * 16 + lrow * 4;
#pragma unroll
      for (int r = 0; r < 4; ++r)
        gates[(mbase + r) * 512 + n] = f2bf(acc[im][in][r] + bias);
    }
  }
}

// ---------------- Kernel 2: sequential masked LSTM ----------------
// 64 blocks x 512 threads; block handles 4 batches [4b, 4b+4).
// Transposed MFMA: gates^T = W_hh @ h^T (operands swapped vs h@W_hh^T).
// D cols = batch slots (replicated mod 4), D rows = h-cols -> every lane holds
// all 4 gates for ONE (batch,hcol) unit at reg index q = lcol>>2. One barrier/step.
__global__ __launch_bounds__(512) void k2_lstm(const float* __restrict__ done,
                                               const float* __restrict__ h0,
                                               const float* __restrict__ c0,
                                               const u16* __restrict__ whh_bf,
                                               const u16* __restrict__ gates,
                                               u16* __restrict__ hseq,
                                               float* __restrict__ dout) {
  __shared__ __align__(16) u16 h_lds[2][4][136];
  const int tid = threadIdx.x;
  const int lane = tid & 63;
  const int w = tid >> 6;            // 0..7, owns h-cols [16w,16w+16)
  const int lrow = lane >> 4, lcol = lane & 15;
  const int bbase = blockIdx.x * 4;
  const int jb = w * 16;
  const int q = lcol >> 2;           // reg index to select
  const int bt = lcol & 3;           // batch slot (replicated x4 in MFMA cols)
  const int hc = jb + lrow * 4 + q;  // this lane's h-column
  const int brow = bbase + bt;       // global batch index

  // Preload W_hh A-operand fragments (gatecol = g*128 + jb + lcol), 64 VGPRs, reused 512x
  bfrag8 wf[4][4];
#pragma unroll
  for (int g = 0; g < 4; ++g)
#pragma unroll
    for (int kk = 0; kk < 4; ++kk)
      wf[g][kk] = *(const bfrag8*)&whh_bf[(g * 128 + jb + lcol) * 128 + kk * 32 + lrow * 8];

  // init: each thread owns exactly one (bt, hc)
  const float m0v = 1.0f - done[brow];
  h_lds[0][bt][hc] = f2bf(h0[brow * 128 + hc] * m0v);
  float c = c0[brow * 128 + hc] * m0v;
  float hfin = 0.0f;

  // prefetch gates(t=0) and done(t=1)
  u32 gp[4], gpn[4];
#pragma unroll
  for (int g = 0; g < 4; ++g)
    gp[g] = gates[brow * 512 + g * 128 + hc];
  float dnx = done[B_ + brow];
  float dn2;

  for (int t = 0; t < T_; ++t) {
    const int cur = t & 1, nxt = cur ^ 1;
    __syncthreads();  // h_lds[cur] visible; prefetched gp loads drained

    const int tn = (t + 1 < T_) ? t + 1 : T_ - 1;
    const int t2 = (t + 2 < T_) ? t + 2 : T_ - 1;
#pragma unroll
    for (int g = 0; g < 4; ++g)
      gpn[g] = gates[(tn * B_ + brow) * 512 + g * 128 + hc];
    dn2 = done[t2 * B_ + brow];
    const float live = (t < T_ - 1) ? 1.0f : 0.0f;
    const float mk = 1.0f - live * dnx;

    // h^T B-operand fragments (batch slot = lcol&3)
    bfrag8 hf[4];
#pragma unroll
    for (int kk = 0; kk < 4; ++kk)
      hf[kk] = *(const bfrag8*)&h_lds[cur][bt][kk * 32 + lrow * 8];

    f32x4 acc[4] = {};
#pragma unroll
    for (int kk = 0; kk < 4; ++kk)
#pragma unroll
      for (int g = 0; g < 4; ++g)
        acc[g] = mfma16(wf[g][kk], hf[kk], acc[g]);

    float pi = sel4(acc[0], q) + bf2f((u16)gp[0]);
    float pf = sel4(acc[1], q) + bf2f((u16)gp[1]);
    float pg = sel4(acc[2], q) + bf2f((u16)gp[2]);
    float po = sel4(acc[3], q) + bf2f((u16)gp[3]);
    float iv = sig_(pi), fv = sig_(pf), gv = tanh_(pg), ov = sig_(po);
    float cc = fv * c + iv * gv;
    float hh = ov * tanh_(cc);
    c = cc * mk;
    hfin = hh;
    hseq[((t * B_ + brow) << 7) + hc] = f2bf(hh);
    h_lds[nxt][bt][hc] = f2bf(hh * mk);

#pragma unroll
    for (int g = 0; g < 4; ++g) gp[g] = gpn[g];
    dnx = dn2;
  }
  // hT, cT (fp32)
  dout[OUT0 + brow * 128 + hc] = hfin;
  dout[OUT0 + OUT1 + brow * 128 + hc] = c;
}

// ---------------- Kernel 3: MLP heads ----------------
__global__ __launch_bounds__(256) void k3_heads(const u16* __restrict__ hseq,
                                                const u16* __restrict__ wp1s,
                                                const u16* __restrict__ wv1s,
                                                const float* __restrict__ b_p1,
                                                const float* __restrict__ W_p2,
                                                const float* __restrict__ b_p2,
                                                const float* __restrict__ b_v1,
                                                const float* __restrict__ W_v2,
                                                const float* __restrict__ b_v2,
                                                float* __restrict__ out) {
  __shared__ float midp[4][16][68];
  __shared__ float midv[4][16][68];
  __shared__ float wsm[585];  // W_p2(512) ++ W_v2(64) ++ b_p2(8) ++ b_v2(1)
  const int tid = threadIdx.x;
  const int lane = tid & 63, w = tid >> 6;
  const int lrow = lane >> 4, lcol = lane & 15;
  const int r0 = blockIdx.x * 64;

  for (int e = tid; e < 585; e += 256) {
    float v;
    if (e < 512) v = W_p2[e];
    else if (e < 576) v = W_v2[e - 512];
    else if (e < 584) v = b_p2[e - 576];
    else v = b_v2[0];
    wsm[e] = v;
  }

  const int rowA = r0 + w * 16 + lcol;
  bfrag8 af[4];
#pragma unroll
  for (int kk = 0; kk < 4; ++kk)
    af[kk] = *(const bfrag8*)&hseq[rowA * 128 + kk * 32 + lrow * 8];

#pragma unroll
  for (int nt = 0; nt < 4; ++nt) {
    f32x4 ap = {}, av = {};
#pragma unroll
    for (int kk = 0; kk < 4; ++kk) {
      ap = mfma16(af[kk], *(const bfrag8*)&wp1s[((nt * 4 + kk) * 64 + lane) * 8], ap);
      av = mfma16(af[kk], *(const bfrag8*)&wv1s[((nt * 4 + kk) * 64 + lane) * 8], av);
    }
    float bp = b_p1[nt * 16 + lcol], bv = b_v1[nt * 16 + lcol];
#pragma unroll
    for (int r = 0; r < 4; ++r) {
      midp[w][lrow * 4 + r][nt * 16 + lcol] = tanh_(ap[r] + bp);
      midv[w][lrow * 4 + r][nt * 16 + lcol] = tanh_(av[r] + bv);
    }
  }
  __syncthreads();

  for (int o = tid; o < 576; o += 256) {
    int row = o / 9;
    int a = o - row * 9;
    float s;
    if (a < 8) {
      s = wsm[576 + a];
      const float* mrow = &midp[row >> 4][row & 15][0];
#pragma unroll
      for (int n = 0; n < 64; ++n) s += mrow[n] * wsm[n * 8 + a];
    } else {
      s = wsm[584];
      const float* mrow = &midv[row >> 4][row & 15][0];
#pragma unroll
      for (int n = 0; n < 64; ++n) s += mrow[n] * wsm[512 + n];
    }
    out[(r0 + row) * 9 + a] = s;
  }
}

extern "C" void kernel_launch(void* const* d_in, const int* in_sizes, int n_in,
                              void* d_out, int out_size, void* d_ws, size_t ws_size,
                              hipStream_t stream) {
  const float* x    = (const float*)d_in[0];
  const float* done = (const float*)d_in[1];
  const float* h0   = (const float*)d_in[2];
  const float* c0   = (const float*)d_in[3];
  const float* W_ih = (const float*)d_in[4];
  const float* W_hh = (const float*)d_in[5];
  const float* b_ih = (const float*)d_in[6];
  const float* b_hh = (const float*)d_in[7];
  const float* W_p1 = (const float*)d_in[8];
  const float* b_p1 = (const float*)d_in[9];
  const float* W_p2 = (const float*)d_in[10];
  const float* b_p2 = (const float*)d_in[11];
  const float* W_v1 = (const float*)d_in[12];
  const float* b_v1 = (const float*)d_in[13];
  const float* W_v2 = (const float*)d_in[14];
  const float* b_v2 = (const float*)d_in[15];

  char* ws = (char*)d_ws;
  u16* gates   = (u16*)(ws + WS_GATES);
  u16* hseq    = (u16*)(ws + WS_HSEQ);
  u16* wih_swz = (u16*)(ws + WS_WIH);
  u16* whh_bf  = (u16*)(ws + WS_WHH);
  u16* wp1s    = (u16*)(ws + WS_WP1);
  u16* wv1s    = (u16*)(ws + WS_WV1);
  float* out = (float*)d_out;

  k0_prep<<<dim3(1344), dim3(256), 0, stream>>>(W_ih, W_hh, W_p1, W_v1,
                                                wih_swz, whh_bf, wp1s, wv1s);
  k1_gates<<<dim3(1024), dim3(512), 0, stream>>>(x, wih_swz, b_ih, b_hh, gates);
  k2_lstm<<<dim3(64), dim3(512), 0, stream>>>(done, h0, c0, whh_bf, gates, hseq, out);
  k3_heads<<<dim3(2048), dim3(256), 0, stream>>>(hseq, wp1s, wv1s, b_p1, W_p2, b_p2,
                                                 b_v1, W_v2, b_v2, out);
}